// Round 1
// baseline (938.725 us; speedup 1.0000x reference)
//
#include <hip/hip_runtime.h>
#include <math.h>

// Problem constants (from reference): B=1024, T=256, D=128, H=64, 4H=256
constexpr int B_ = 1024;
constexpr int T_ = 256;
constexpr int D_ = 128;
constexpr int H_ = 64;
constexpr int G_ = 4 * H_;  // 256 gate rows

__device__ __forceinline__ float sigmoidf_(float x) {
    // safe: x -> -inf gives exp(+inf)=inf -> 1/inf = 0; x -> +inf gives 1.
    return 1.0f / (1.0f + __expf(-x));
}

__device__ __forceinline__ float tanhf_(float x) {
    // overflow-safe tanh: exp of a non-positive argument only
    float ax = fabsf(x);
    float e  = __expf(-2.0f * ax);
    float t  = (1.0f - e) / (1.0f + e);
    return copysignf(t, x);
}

// One block per batch element. Thread g (0..255) owns gate row g:
// W_ih[g,:] (128 f32) + W_hh[g,:] (64 f32) live in VGPRs for the whole
// kernel (~192 VGPRs -> launch_bounds(256,2) caps at 256, 2 waves/SIMD).
// x_t and h are broadcast from LDS (same-address reads = free broadcast).
__global__ __launch_bounds__(256, 2)
void lstm_fused_kernel(const float* __restrict__ x,     // [B,T,D]
                       const float* __restrict__ W_ih,  // [4H,D]
                       const float* __restrict__ W_hh,  // [4H,H]
                       const float* __restrict__ b_ih,  // [4H]
                       const float* __restrict__ b_hh,  // [4H]
                       const float* __restrict__ W1,    // [32,H]
                       const float* __restrict__ b1,    // [32]
                       const float* __restrict__ W2,    // [1,32]
                       const float* __restrict__ b2,    // [1]
                       float* __restrict__ out)         // [B]
{
    const int b = blockIdx.x;
    const int g = threadIdx.x;

    __shared__ __align__(16) float xs[D_];     // current x row
    __shared__ __align__(16) float hs[H_];     // hidden state
    __shared__ __align__(16) float gates[G_];  // post-activation gates
    __shared__ __align__(16) float ys[32];     // head hidden

    // ---- preload this thread's weight rows into registers ----
    float wih[D_];
    float whh[H_];
    {
        const float4* wr = (const float4*)(W_ih + (size_t)g * D_);
        #pragma unroll
        for (int k = 0; k < D_ / 4; ++k) {
            float4 v = wr[k];
            wih[4*k+0] = v.x; wih[4*k+1] = v.y;
            wih[4*k+2] = v.z; wih[4*k+3] = v.w;
        }
    }
    {
        const float4* wr = (const float4*)(W_hh + (size_t)g * H_);
        #pragma unroll
        for (int k = 0; k < H_ / 4; ++k) {
            float4 v = wr[k];
            whh[4*k+0] = v.x; whh[4*k+1] = v.y;
            whh[4*k+2] = v.z; whh[4*k+3] = v.w;
        }
    }
    const float bg  = b_ih[g] + b_hh[g];
    const int   cls = g >> 6;  // 0:i 1:f 2:g 3:o  (wave-uniform branch)

    float c = 0.0f;            // cell state, owned by threads 0..63
    if (g < H_) hs[g] = 0.0f;

    const float* __restrict__ xrow = x + (size_t)b * T_ * D_;

    for (int t = 0; t < T_; ++t) {
        // stage x_t (coalesced, 128 lanes x 4B)
        if (g < D_) xs[g] = xrow[(size_t)t * D_ + g];
        __syncthreads();  // also orders previous step's hs write vs reads below

        // gate matvec: 4 independent accumulator chains for ILP
        float a0 = bg, a1 = 0.f, a2 = 0.f, a3 = 0.f;
        const float4* xs4 = (const float4*)xs;
        #pragma unroll
        for (int k = 0; k < D_ / 4; ++k) {
            float4 v = xs4[k];
            a0 = fmaf(wih[4*k+0], v.x, a0);
            a1 = fmaf(wih[4*k+1], v.y, a1);
            a2 = fmaf(wih[4*k+2], v.z, a2);
            a3 = fmaf(wih[4*k+3], v.w, a3);
        }
        const float4* hs4 = (const float4*)hs;
        #pragma unroll
        for (int k = 0; k < H_ / 4; ++k) {
            float4 v = hs4[k];
            a0 = fmaf(whh[4*k+0], v.x, a0);
            a1 = fmaf(whh[4*k+1], v.y, a1);
            a2 = fmaf(whh[4*k+2], v.z, a2);
            a3 = fmaf(whh[4*k+3], v.w, a3);
        }
        float acc = (a0 + a1) + (a2 + a3);
        gates[g] = (cls == 2) ? tanhf_(acc) : sigmoidf_(acc);
        __syncthreads();

        // elementwise cell/hidden update (threads 0..63)
        if (g < H_) {
            float gi = gates[g];
            float gf = gates[H_ + g];
            float gg = gates[2 * H_ + g];
            float go = gates[3 * H_ + g];
            c = fmaf(gf, c, gi * gg);
            hs[g] = go * tanhf_(c);
        }
        // hs-write vs next-step hs-read is ordered by next iteration's barrier
    }
    __syncthreads();

    // ---- head: relu(h @ W1^T + b1) -> sigmoid(@ W2^T + b2) ----
    if (g < 32) {
        float acc = b1[g];
        const float* w1r = W1 + g * H_;
        #pragma unroll
        for (int k = 0; k < H_; ++k) acc = fmaf(w1r[k], hs[k], acc);
        ys[g] = fmaxf(acc, 0.0f);
    }
    __syncthreads();
    if (g == 0) {
        float acc = b2[0];
        #pragma unroll
        for (int k = 0; k < 32; ++k) acc = fmaf(W2[k], ys[k], acc);
        out[b] = sigmoidf_(acc);
    }
}

extern "C" void kernel_launch(void* const* d_in, const int* in_sizes, int n_in,
                              void* d_out, int out_size, void* d_ws, size_t ws_size,
                              hipStream_t stream) {
    const float* x    = (const float*)d_in[0];
    const float* W_ih = (const float*)d_in[1];
    const float* W_hh = (const float*)d_in[2];
    const float* b_ih = (const float*)d_in[3];
    const float* b_hh = (const float*)d_in[4];
    const float* W1   = (const float*)d_in[5];
    const float* b1   = (const float*)d_in[6];
    const float* W2   = (const float*)d_in[7];
    const float* b2   = (const float*)d_in[8];
    float* out = (float*)d_out;

    lstm_fused_kernel<<<dim3(B_), dim3(256), 0, stream>>>(
        x, W_ih, W_hh, b_ih, b_hh, W1, b1, W2, b2, out);
}

// Round 2
// 461.237 us; speedup vs baseline: 2.0352x; 2.0352x over previous
//
#include <hip/hip_runtime.h>
#include <math.h>

// Problem constants: B=1024, T=256, D=128, H=64, 4H=256
constexpr int B_ = 1024;
constexpr int T_ = 256;
constexpr int D_ = 128;
constexpr int H_ = 64;
constexpr int G_ = 4 * H_;        // 256 gate rows
constexpr int M_ = B_ * T_;       // 262144 rows of x / x_proj

typedef short  v8s  __attribute__((ext_vector_type(8)));   // 8 bf16 (4 VGPRs)
typedef float  v4f  __attribute__((ext_vector_type(4)));   // MFMA acc

__device__ __forceinline__ float sigmoidf_(float x) {
    return 1.0f / (1.0f + __expf(-x));
}
__device__ __forceinline__ float tanhf_(float x) {
    float ax = fabsf(x);
    float e  = __expf(-2.0f * ax);
    float t  = (1.0f - e) / (1.0f + e);
    return copysignf(t, x);
}
__device__ __forceinline__ unsigned short f2bf(float f) {   // RNE f32->bf16
    unsigned u = __float_as_uint(f);
    u = (u + 0x7fffu + ((u >> 16) & 1u)) >> 16;
    return (unsigned short)u;
}
__device__ __forceinline__ float bf2f(unsigned short s) {
    return __uint_as_float(((unsigned)s) << 16);
}

// ---------------------------------------------------------------------------
// Phase 1: x_proj[M,256] (bf16) = x[M,128] @ W_ih^T[128,256], fp32 accumulate.
// Block: 256 thr (4 waves). Block tile: BM=128 rows x BN=64 cols. K=128 whole.
// Wave w computes rows [w*32, w*32+32) x all 64 cols: 2 mt x 4 nt x 4 kk MFMAs.
// LDS padded +8 bf16/row so column-strided frag reads are 2-way (free).
// ---------------------------------------------------------------------------
constexpr int BM_ = 128;
constexpr int BN_ = 64;
constexpr int LDA_ = D_ + 8;      // 136 shorts per row (272B, 16B-aligned rows)

__global__ __launch_bounds__(256, 2)
void xproj_mfma_kernel(const float* __restrict__ x,       // [M,128]
                       const float* __restrict__ W_ih,    // [256,128]
                       unsigned short* __restrict__ xp)   // [M,256] bf16
{
    const int nblk = blockIdx.x;          // fast: 4 nblks share x rows (L2 reuse)
    const int mblk = blockIdx.y;
    const int mbase = mblk * BM_;
    const int nbase = nblk * BN_;
    const int tid = threadIdx.x;

    __shared__ __align__(16) unsigned short As[BM_][LDA_];  // 34.8 KB
    __shared__ __align__(16) unsigned short Bs[BN_][LDA_];  // 17.4 KB

    // ---- stage A tile: 128x128 f32 -> bf16 LDS (16 float4 per thread) ----
    #pragma unroll
    for (int i = 0; i < 16; ++i) {
        int f4 = tid + i * 256;           // 4096 float4s total
        int row = f4 >> 5, c4 = f4 & 31;
        float4 v = ((const float4*)(x + (size_t)(mbase + row) * D_))[c4];
        short4 s; s.x = f2bf(v.x); s.y = f2bf(v.y); s.z = f2bf(v.z); s.w = f2bf(v.w);
        *(short4*)&As[row][c4 * 4] = s;
    }
    // ---- stage B tile: W_ih rows [nbase, nbase+64) ----
    #pragma unroll
    for (int i = 0; i < 8; ++i) {
        int f4 = tid + i * 256;           // 2048 float4s total
        int row = f4 >> 5, c4 = f4 & 31;
        float4 v = ((const float4*)(W_ih + (size_t)(nbase + row) * D_))[c4];
        short4 s; s.x = f2bf(v.x); s.y = f2bf(v.y); s.z = f2bf(v.z); s.w = f2bf(v.w);
        *(short4*)&Bs[row][c4 * 4] = s;
    }
    __syncthreads();

    const int w = tid >> 6, lane = tid & 63;
    const int q = lane >> 4, ml = lane & 15;

    v4f acc[2][4];
    #pragma unroll
    for (int mt = 0; mt < 2; ++mt)
        #pragma unroll
        for (int nt = 0; nt < 4; ++nt)
            acc[mt][nt] = (v4f)(0.0f);

    #pragma unroll
    for (int kk = 0; kk < 4; ++kk) {
        const int koff = kk * 32 + q * 8;
        v8s a[2], b[4];
        #pragma unroll
        for (int mt = 0; mt < 2; ++mt)
            a[mt] = *(const v8s*)&As[w * 32 + mt * 16 + ml][koff];
        #pragma unroll
        for (int nt = 0; nt < 4; ++nt)
            b[nt] = *(const v8s*)&Bs[nt * 16 + ml][koff];
        #pragma unroll
        for (int mt = 0; mt < 2; ++mt)
            #pragma unroll
            for (int nt = 0; nt < 4; ++nt)
                acc[mt][nt] = __builtin_amdgcn_mfma_f32_16x16x32_bf16(
                    a[mt], b[nt], acc[mt][nt], 0, 0, 0);
    }

    // ---- epilogue: D[row=(q*4+r)][col=ml] per 16x16 tile -> bf16 global ----
    #pragma unroll
    for (int mt = 0; mt < 2; ++mt)
        #pragma unroll
        for (int nt = 0; nt < 4; ++nt)
            #pragma unroll
            for (int r = 0; r < 4; ++r) {
                int grow = mbase + w * 32 + mt * 16 + q * 4 + r;
                int gcol = nbase + nt * 16 + ml;
                xp[(size_t)grow * G_ + gcol] = f2bf(acc[mt][nt][r]);
            }
}

// ---------------------------------------------------------------------------
// Phase 2: recurrence. One block per batch element, thread g owns gate row g.
// Only W_hh[g,:] (64 f32) in regs -> ~100 VGPR -> 4 blocks/CU, single pass.
// ---------------------------------------------------------------------------
__global__ __launch_bounds__(256, 4)
void lstm_rec_kernel(const unsigned short* __restrict__ xp,  // [M,256] bf16
                     const float* __restrict__ W_hh,   // [4H,H]
                     const float* __restrict__ b_ih,   // [4H]
                     const float* __restrict__ b_hh,   // [4H]
                     const float* __restrict__ W1,     // [32,H]
                     const float* __restrict__ b1,     // [32]
                     const float* __restrict__ W2,     // [1,32]
                     const float* __restrict__ b2,     // [1]
                     float* __restrict__ out)          // [B]
{
    const int b = blockIdx.x;
    const int g = threadIdx.x;

    __shared__ __align__(16) float hs[H_];
    __shared__ __align__(16) float gates[G_];
    __shared__ __align__(16) float ys[32];

    float whh[H_];
    {
        const float4* wr = (const float4*)(W_hh + (size_t)g * H_);
        #pragma unroll
        for (int k = 0; k < H_ / 4; ++k) {
            float4 v = wr[k];
            whh[4*k+0] = v.x; whh[4*k+1] = v.y;
            whh[4*k+2] = v.z; whh[4*k+3] = v.w;
        }
    }
    const float bg  = b_ih[g] + b_hh[g];
    const int   cls = g >> 6;             // wave-uniform gate class

    float c = 0.0f;
    if (g < H_) hs[g] = 0.0f;

    const unsigned short* __restrict__ xrow = xp + (size_t)b * T_ * G_ + g;

    for (int t = 0; t < T_; ++t) {
        float xpv = bf2f(xrow[(size_t)t * G_]);
        __syncthreads();                  // orders prev hs write vs reads below

        float a0 = bg + xpv, a1 = 0.f, a2 = 0.f, a3 = 0.f;
        const float4* hs4 = (const float4*)hs;
        #pragma unroll
        for (int k = 0; k < H_ / 4; ++k) {
            float4 v = hs4[k];
            a0 = fmaf(whh[4*k+0], v.x, a0);
            a1 = fmaf(whh[4*k+1], v.y, a1);
            a2 = fmaf(whh[4*k+2], v.z, a2);
            a3 = fmaf(whh[4*k+3], v.w, a3);
        }
        float accv = (a0 + a1) + (a2 + a3);
        gates[g] = (cls == 2) ? tanhf_(accv) : sigmoidf_(accv);
        __syncthreads();

        if (g < H_) {
            float gi = gates[g];
            float gf = gates[H_ + g];
            float gg = gates[2 * H_ + g];
            float go = gates[3 * H_ + g];
            c = fmaf(gf, c, gi * gg);
            hs[g] = go * tanhf_(c);
        }
    }
    __syncthreads();

    if (g < 32) {
        float acc = b1[g];
        const float* w1r = W1 + g * H_;
        #pragma unroll
        for (int k = 0; k < H_; ++k) acc = fmaf(w1r[k], hs[k], acc);
        ys[g] = fmaxf(acc, 0.0f);
    }
    __syncthreads();
    if (g == 0) {
        float acc = b2[0];
        #pragma unroll
        for (int k = 0; k < 32; ++k) acc = fmaf(W2[k], ys[k], acc);
        out[b] = sigmoidf_(acc);
    }
}

// ---------------------------------------------------------------------------
// Fallback (round-1 fused fp32 kernel) if workspace is too small for x_proj.
// ---------------------------------------------------------------------------
__global__ __launch_bounds__(256, 2)
void lstm_fused_kernel(const float* __restrict__ x,
                       const float* __restrict__ W_ih,
                       const float* __restrict__ W_hh,
                       const float* __restrict__ b_ih,
                       const float* __restrict__ b_hh,
                       const float* __restrict__ W1,
                       const float* __restrict__ b1,
                       const float* __restrict__ W2,
                       const float* __restrict__ b2,
                       float* __restrict__ out)
{
    const int b = blockIdx.x;
    const int g = threadIdx.x;

    __shared__ __align__(16) float xs[D_];
    __shared__ __align__(16) float hs[H_];
    __shared__ __align__(16) float gates[G_];
    __shared__ __align__(16) float ys[32];

    float wih[D_];
    float whh[H_];
    {
        const float4* wr = (const float4*)(W_ih + (size_t)g * D_);
        #pragma unroll
        for (int k = 0; k < D_ / 4; ++k) {
            float4 v = wr[k];
            wih[4*k+0] = v.x; wih[4*k+1] = v.y;
            wih[4*k+2] = v.z; wih[4*k+3] = v.w;
        }
    }
    {
        const float4* wr = (const float4*)(W_hh + (size_t)g * H_);
        #pragma unroll
        for (int k = 0; k < H_ / 4; ++k) {
            float4 v = wr[k];
            whh[4*k+0] = v.x; whh[4*k+1] = v.y;
            whh[4*k+2] = v.z; whh[4*k+3] = v.w;
        }
    }
    const float bg  = b_ih[g] + b_hh[g];
    const int   cls = g >> 6;

    float c = 0.0f;
    if (g < H_) hs[g] = 0.0f;

    const float* __restrict__ xrow = x + (size_t)b * T_ * D_;

    for (int t = 0; t < T_; ++t) {
        if (g < D_) xs[g] = xrow[(size_t)t * D_ + g];
        __syncthreads();

        float a0 = bg, a1 = 0.f, a2 = 0.f, a3 = 0.f;
        const float4* xs4 = (const float4*)xs;
        #pragma unroll
        for (int k = 0; k < D_ / 4; ++k) {
            float4 v = xs4[k];
            a0 = fmaf(wih[4*k+0], v.x, a0);
            a1 = fmaf(wih[4*k+1], v.y, a1);
            a2 = fmaf(wih[4*k+2], v.z, a2);
            a3 = fmaf(wih[4*k+3], v.w, a3);
        }
        const float4* hs4 = (const float4*)hs;
        #pragma unroll
        for (int k = 0; k < H_ / 4; ++k) {
            float4 v = hs4[k];
            a0 = fmaf(whh[4*k+0], v.x, a0);
            a1 = fmaf(whh[4*k+1], v.y, a1);
            a2 = fmaf(whh[4*k+2], v.z, a2);
            a3 = fmaf(whh[4*k+3], v.w, a3);
        }
        float acc = (a0 + a1) + (a2 + a3);
        gates[g] = (cls == 2) ? tanhf_(acc) : sigmoidf_(acc);
        __syncthreads();

        if (g < H_) {
            float gi = gates[g];
            float gf = gates[H_ + g];
            float gg = gates[2 * H_ + g];
            float go = gates[3 * H_ + g];
            c = fmaf(gf, c, gi * gg);
            hs[g] = go * tanhf_(c);
        }
    }
    __syncthreads();

    if (g < 32) {
        float acc = b1[g];
        const float* w1r = W1 + g * H_;
        #pragma unroll
        for (int k = 0; k < H_; ++k) acc = fmaf(w1r[k], hs[k], acc);
        ys[g] = fmaxf(acc, 0.0f);
    }
    __syncthreads();
    if (g == 0) {
        float acc = b2[0];
        #pragma unroll
        for (int k = 0; k < 32; ++k) acc = fmaf(W2[k], ys[k], acc);
        out[b] = sigmoidf_(acc);
    }
}

extern "C" void kernel_launch(void* const* d_in, const int* in_sizes, int n_in,
                              void* d_out, int out_size, void* d_ws, size_t ws_size,
                              hipStream_t stream) {
    const float* x    = (const float*)d_in[0];
    const float* W_ih = (const float*)d_in[1];
    const float* W_hh = (const float*)d_in[2];
    const float* b_ih = (const float*)d_in[3];
    const float* b_hh = (const float*)d_in[4];
    const float* W1   = (const float*)d_in[5];
    const float* b1   = (const float*)d_in[6];
    const float* W2   = (const float*)d_in[7];
    const float* b2   = (const float*)d_in[8];
    float* out = (float*)d_out;

    const size_t xp_bytes = (size_t)M_ * G_ * sizeof(unsigned short);  // 134 MB

    if (ws_size >= xp_bytes) {
        unsigned short* xp = (unsigned short*)d_ws;
        // Phase 1: 8192 blocks (nblk fast for x-row reuse across the 4 nblks)
        xproj_mfma_kernel<<<dim3(G_ / BN_, M_ / BM_), dim3(256), 0, stream>>>(
            x, W_ih, xp);
        // Phase 2: recurrence, one pass (1024 blocks, 4/CU)
        lstm_rec_kernel<<<dim3(B_), dim3(256), 0, stream>>>(
            xp, W_hh, b_ih, b_hh, W1, b1, W2, b2, out);
    } else {
        lstm_fused_kernel<<<dim3(B_), dim3(256), 0, stream>>>(
            x, W_ih, W_hh, b_ih, b_hh, W1, b1, W2, b2, out);
    }
}